// Round 1
// 95.005 us; speedup vs baseline: 1.0084x; 1.0084x over previous
//
#include <hip/hip_runtime.h>
#include <math.h>

#define BB 8
#define TT 256
#define DD 12
#define HH 4
#define HDIM 3
#define QCHUNK 16            // queries per block
#define NCHUNK (TT / QCHUNK) // 16 chunks per batch
#define KROWS 260            // 4 chunks of 64 keys + 1 float4 pad per chunk
#define MASK_NEG -3.0e38f

// ---------------------------------------------------------------------------
// Closed-form measurement of the n_layers=2 circuit (one CNOT ring):
//   <Z_w> = prod_{j=0..w} z_j (w>=1),  <Z_0> = prod_{j=1..11} z_j
// ---------------------------------------------------------------------------
__device__ __forceinline__ void ring_measure(const float* z, float* outp)
{
    float pref = 1.0f;
#pragma unroll
    for (int j = 0; j < DD; ++j) { pref *= z[j]; outp[j] = pref; }
    float suf = 1.0f;
#pragma unroll
    for (int j = 1; j < DD; ++j) suf *= z[j];
    outp[0] = suf;
}

__device__ __forceinline__ void layer_norm(float* v, const float* __restrict__ g,
                                           const float* __restrict__ b)
{
    float mean = 0.f;
#pragma unroll
    for (int j = 0; j < DD; ++j) mean += v[j];
    mean *= (1.0f / DD);
    float var = 0.f;
#pragma unroll
    for (int j = 0; j < DD; ++j) { float d = v[j] - mean; var = fmaf(d, d, var); }
    var *= (1.0f / DD);
    const float r = rsqrtf(var + 1e-5f);
#pragma unroll
    for (int j = 0; j < DD; ++j) v[j] = (v[j] - mean) * r * g[j] + b[j];
}

// ---------------------------------------------------------------------------
// Single fused kernel. Grid = B * (T/16) = 128 blocks x 256 threads.
// Block = (b, 16-query chunk). Thread t -> (head w = t>>6, key-quarter
// ks = (t>>4)&3, query q = t&15).
// Phase A: all 256 threads build K/V for ALL 256 keys x 4 heads of batch b
//          into LDS (redundant across the 16 chunks of b — 288 fma/thread,
//          cheap). Key k stored at padded slot (k>>6)*65 + (k&63) so the 4
//          broadcast groups in phase C hit disjoint bank sets.
// Phase C: identical 64-key exp-partial loop as the previous attn_partial
//          kernel (softmax without max-subtraction; partials combine
//          linearly), partials exchanged through LDS instead of global.
// Phase D: threads 0..15 run the verified per-token tail (merge -> out-proj
//          -> closed-form attn circuit -> LN1 -> lin1 -> closed-form FFN
//          circuit -> lin2+ReLU -> LN2).
// One launch; workspace unused.
// ---------------------------------------------------------------------------
__global__ __launch_bounds__(256) void fused_block_kernel(
    const float* __restrict__ x,     // [B,T,D]
    const float* __restrict__ wi,    // [3D,D]
    const float* __restrict__ bi,    // [3D]
    const int*   __restrict__ mask,  // [B,T]
    const float* __restrict__ wo, const float* __restrict__ bo,
    const float* __restrict__ th_a,
    const float* __restrict__ w1, const float* __restrict__ b1,
    const float* __restrict__ th_f,
    const float* __restrict__ w2, const float* __restrict__ b2,
    const float* __restrict__ g1, const float* __restrict__ be1,
    const float* __restrict__ g2, const float* __restrict__ be2,
    float* __restrict__ out)
{
    const int b  = blockIdx.x >> 4;   // batch
    const int qc = blockIdx.x & 15;   // query chunk within batch
    const int t  = threadIdx.x;
    const int w  = t >> 6;            // head (wave index)
    const int l  = t & 63;
    const int ks = l >> 4;            // key quarter
    const int q  = l & 15;            // query within chunk

    __shared__ float4 kk4[HH][KROWS]; // {k0,k1,k2, maskbias}, padded layout
    __shared__ float4 vv4[HH][KROWS]; // {v0,v1,v2, 0}
    __shared__ float4 hp[HH][4][QCHUNK]; // per-(head,quarter,query) partials

    // ---- Phase A: K/V for key token t (all 4 heads) ----
    {
        const float4* kr4 = (const float4*)(x + (b * TT + t) * DD);
        const float4 c0 = kr4[0], c1 = kr4[1], c2 = kr4[2];
        const float kvv[DD] = {c0.x, c0.y, c0.z, c0.w, c1.x, c1.y, c1.z, c1.w,
                               c2.x, c2.y, c2.z, c2.w};
        const float mb = (mask[b * TT + t] != 0) ? MASK_NEG : 0.0f;
        const int slot = (t >> 6) * 65 + (t & 63);
#pragma unroll
        for (int h = 0; h < HH; ++h) {
            float kx[HDIM], vx[HDIM];
#pragma unroll
            for (int d = 0; d < HDIM; ++d) {
                const int rk = DD + h * HDIM + d;
                const int rv = 2 * DD + h * HDIM + d;
                float ak = bi[rk], av = bi[rv];
#pragma unroll
                for (int j = 0; j < DD; ++j) {
                    ak = fmaf(wi[rk * DD + j], kvv[j], ak);
                    av = fmaf(wi[rv * DD + j], kvv[j], av);
                }
                kx[d] = ak; vx[d] = av;
            }
            kk4[h][slot] = make_float4(kx[0], kx[1], kx[2], mb);
            vv4[h][slot] = make_float4(vx[0], vx[1], vx[2], 0.0f);
        }
    }

    // ---- Phase B: q for (head w, query qc*16+q), pre-scaled by 1/sqrt(3) ----
    float qs[HDIM];
    {
        const float4* xr4 = (const float4*)(x + (b * TT + qc * QCHUNK + q) * DD);
        const float4 p0 = xr4[0], p1 = xr4[1], p2 = xr4[2];
        const float xv[DD] = {p0.x, p0.y, p0.z, p0.w, p1.x, p1.y, p1.z, p1.w,
                              p2.x, p2.y, p2.z, p2.w};
        const float scale = 0.57735026918962576f; // 1/sqrt(3)
#pragma unroll
        for (int d = 0; d < HDIM; ++d) {
            const int rq = w * HDIM + d;
            float a = bi[rq];
#pragma unroll
            for (int j = 0; j < DD; ++j) a = fmaf(wi[rq * DD + j], xv[j], a);
            qs[d] = a * scale;
        }
    }
    __syncthreads();

    // ---- Phase C: 64-key partial (4 independent fma chains, no max-sub) ----
    {
        const int kbase = ks * 65;   // padded base of this key quarter
        float sum = 0.f, a0 = 0.f, a1 = 0.f, a2 = 0.f;
#pragma unroll
        for (int k = 0; k < 64; ++k) {
            const float4 kk = kk4[w][kbase + k];
            const float4 vv = vv4[w][kbase + k];
            const float s = fmaf(qs[0], kk.x, fmaf(qs[1], kk.y, fmaf(qs[2], kk.z, kk.w)));
            const float e = __expf(s);
            sum += e;
            a0 = fmaf(e, vv.x, a0);
            a1 = fmaf(e, vv.y, a1);
            a2 = fmaf(e, vv.z, a2);
        }
        hp[w][ks][q] = make_float4(sum, a0, a1, a2);
    }
    __syncthreads();

    // ---- Phase D: per-token tail on threads 0..15 ----
    if (t < QCHUNK) {
        const int n = b * TT + qc * QCHUNK + t;

        // merge attention partials: linear combine, one divide per head
        float hv[DD];
#pragma unroll
        for (int h = 0; h < HH; ++h) {
            const float4 p0 = hp[h][0][t];
            const float4 p1 = hp[h][1][t];
            const float4 p2 = hp[h][2][t];
            const float4 p3 = hp[h][3][t];
            const float s  = (p0.x + p1.x) + (p2.x + p3.x);
            const float inv = __builtin_amdgcn_rcpf(s);
            hv[h * HDIM + 0] = ((p0.y + p1.y) + (p2.y + p3.y)) * inv;
            hv[h * HDIM + 1] = ((p0.z + p1.z) + (p2.z + p3.z)) * inv;
            hv[h * HDIM + 2] = ((p0.w + p1.w) + (p2.w + p3.w)) * inv;
        }

        // attention out-projection
        float ac[DD];
#pragma unroll
        for (int d = 0; d < DD; ++d) {
            float a = bo[d];
#pragma unroll
            for (int j = 0; j < DD; ++j) a = fmaf(wo[d * DD + j], hv[j], a);
            ac[d] = a;
        }

        // quantum attention circuit: RX(x)·RX(theta) => z = cos(x+theta)
        float z[DD], aq[DD];
#pragma unroll
        for (int j = 0; j < DD; ++j) z[j] = __cosf(ac[j] + th_a[j]);
        ring_measure(z, aq);

        // x1 = LN1(x + attn_q)
        const float4* xr4 = (const float4*)(x + n * DD);
        const float4 x0 = xr4[0], x1q = xr4[1], x2q = xr4[2];
        float x1[DD] = {x0.x, x0.y, x0.z, x0.w, x1q.x, x1q.y, x1q.z, x1q.w,
                        x2q.x, x2q.y, x2q.z, x2q.w};
#pragma unroll
        for (int j = 0; j < DD; ++j) x1[j] += aq[j];
        layer_norm(x1, g1, be1);

        // q_in = x1 @ lin1_w^T + lin1_b
        float qi[DD];
#pragma unroll
        for (int d = 0; d < DD; ++d) {
            float a = b1[d];
#pragma unroll
            for (int j = 0; j < DD; ++j) a = fmaf(w1[d * DD + j], x1[j], a);
            qi[d] = a;
        }

        // quantum FFN circuit: RY(theta)·RX(x) => z = cos(theta)*cos(x)
        float fq[DD];
#pragma unroll
        for (int j = 0; j < DD; ++j) z[j] = __cosf(th_f[j]) * __cosf(qi[j]);
        ring_measure(z, fq);

        // ffn_out = relu(fq @ lin2_w^T + lin2_b); y = x1 + ffn_out; LN2
        float y[DD];
#pragma unroll
        for (int d = 0; d < DD; ++d) {
            float a = b2[d];
#pragma unroll
            for (int j = 0; j < DD; ++j) a = fmaf(w2[d * DD + j], fq[j], a);
            y[d] = fmaxf(a, 0.0f) + x1[d];
        }
        layer_norm(y, g2, be2);

        float4* or4 = (float4*)(out + n * DD);
        or4[0] = make_float4(y[0], y[1], y[2],  y[3]);
        or4[1] = make_float4(y[4], y[5], y[6],  y[7]);
        or4[2] = make_float4(y[8], y[9], y[10], y[11]);
    }
}

extern "C" void kernel_launch(void* const* d_in, const int* in_sizes, int n_in,
                              void* d_out, int out_size, void* d_ws, size_t ws_size,
                              hipStream_t stream)
{
    const float* x    = (const float*)d_in[0];
    const float* wi   = (const float*)d_in[1];   // in_proj_w [36,12]
    const float* bi   = (const float*)d_in[2];   // in_proj_b [36]
    const float* wo   = (const float*)d_in[3];   // out_proj_w [12,12]
    const float* bo   = (const float*)d_in[4];   // out_proj_b [12]
    const float* tha  = (const float*)d_in[5];   // attn_theta [12]
    const float* w1   = (const float*)d_in[6];   // lin1_w [12,12]
    const float* b1   = (const float*)d_in[7];   // lin1_b [12]
    const float* thf  = (const float*)d_in[8];   // ffn_theta [12]
    const float* w2   = (const float*)d_in[9];   // lin2_w [12,12]
    const float* b2   = (const float*)d_in[10];  // lin2_b [12]
    const float* g1   = (const float*)d_in[11];  // ln1_g
    const float* be1  = (const float*)d_in[12];  // ln1_b
    const float* g2   = (const float*)d_in[13];  // ln2_g
    const float* be2  = (const float*)d_in[14];  // ln2_b
    const int*   mask = (const int*)d_in[15];    // mask [8,256]
    float* out = (float*)d_out;
    (void)d_ws; (void)ws_size;                   // workspace no longer used

    fused_block_kernel<<<BB * NCHUNK, 256, 0, stream>>>(
        x, wi, bi, mask, wo, bo, tha, w1, b1, thf, w2, b2,
        g1, be1, g2, be2, out);
}